// Round 1
// baseline (312.088 us; speedup 1.0000x reference)
//
#include <hip/hip_runtime.h>
#include <math.h>

#define Bn 4
#define Cn 64
#define On 64
#define Hn 128
#define Wn 128
#define HWn (Hn * Wn)

// ---------------------------------------------------------------------------
// Kernel 1: x [B,C,H,W] -> x_t [B,HW,C] (channels-last for vectorized gathers)
// ---------------------------------------------------------------------------
__global__ __launch_bounds__(256) void transpose_x_kernel(const float* __restrict__ x,
                                                          float* __restrict__ xt) {
    __shared__ float tile[64][65];  // +1 pad: stride 65 -> conflict-free
    int b = blockIdx.y;
    int hw0 = blockIdx.x * 64;
    int t = threadIdx.x;
    int lane = t & 63;
    int grp = t >> 6;  // 0..3
    const float* xb = x + (size_t)b * Cn * HWn;
#pragma unroll
    for (int i = 0; i < 16; ++i) {
        int c = grp * 16 + i;
        tile[lane][c] = xb[(size_t)c * HWn + hw0 + lane];  // coalesced along hw
    }
    __syncthreads();
    float* xtb = xt + ((size_t)b * HWn + hw0) * Cn;
#pragma unroll
    for (int j = 0; j < 16; ++j) {
        int hw = grp * 16 + j;
        xtb[hw * Cn + lane] = tile[hw][lane];  // coalesced along c
    }
}

// ---------------------------------------------------------------------------
// Kernel 2: w_def [O,C,3,3] -> wdT [k][c][oc]  (36864 floats, tiny)
// ---------------------------------------------------------------------------
__global__ __launch_bounds__(256) void transpose_w_kernel(const float* __restrict__ wdef,
                                                          float* __restrict__ wdT) {
    int idx = blockIdx.x * 256 + threadIdx.x;
    if (idx < 9 * 64 * 64) {
        int oc = idx & 63;
        int c = (idx >> 6) & 63;
        int k = idx >> 12;
        wdT[idx] = wdef[(oc * 64 + c) * 9 + k];
    }
}

// ---------------------------------------------------------------------------
// Kernel 3: offset conv (27 out-ch) + sigmoid on mask planes.
// One thread per pixel, all 27 output channels in registers:
// 243 FMAs per feat load, weights are block-uniform -> scalar loads.
// om layout: [B][27][H][W]; planes 0..8 = off_x, 9..17 = off_y, 18..26 = mask.
// ---------------------------------------------------------------------------
__global__ __launch_bounds__(128) void off_conv_kernel(const float* __restrict__ feat,
                                                       const float* __restrict__ w_off,
                                                       const float* __restrict__ b_off,
                                                       float* __restrict__ om) {
    int w = threadIdx.x;   // 0..127
    int h = blockIdx.x;    // 0..127
    int b = blockIdx.y;    // 0..3

    float acc[27];
#pragma unroll
    for (int i = 0; i < 27; ++i) acc[i] = 0.f;

    const float* fb = feat + (size_t)b * Cn * HWn;
    for (int c = 0; c < Cn; ++c) {
        const float* fc = fb + (size_t)c * HWn;
        float v[9];
#pragma unroll
        for (int ky = 0; ky < 3; ++ky) {
            int y = h + ky - 1;
            bool yv = (y >= 0) && (y < Hn);
#pragma unroll
            for (int kx = 0; kx < 3; ++kx) {
                int xx = w + kx - 1;
                bool ok = yv && (xx >= 0) && (xx < Wn);
                v[ky * 3 + kx] = ok ? fc[y * Wn + xx] : 0.f;
            }
        }
        const float* wc = w_off + c * 9;  // + oc*Cn*9
#pragma unroll
        for (int oc = 0; oc < 27; ++oc) {
            const float* wp = wc + oc * Cn * 9;
#pragma unroll
            for (int kk = 0; kk < 9; ++kk) acc[oc] += v[kk] * wp[kk];
        }
    }

    float* omb = om + (size_t)b * 27 * HWn + h * Wn + w;
#pragma unroll
    for (int oc = 0; oc < 27; ++oc) {
        float vv = acc[oc] + b_off[oc];
        if (oc >= 18) vv = 1.f / (1.f + __expf(-vv));  // sigmoid on mask planes
        omb[(size_t)oc * HWn] = vv;
    }
}

// ---------------------------------------------------------------------------
// Kernel 4: fused deformable sampling + [64px x 64oc] x K=576 contraction.
// Block = 256 threads, tile = 64 consecutive pixels (same row since 64|W).
// ---------------------------------------------------------------------------
#define CSTR 66  // cols row stride (even -> b64 reads 2-way only)
#define WSTR 68  // w-chunk row stride (mult of 4 -> aligned float4)

__global__ __launch_bounds__(256) void fused_kernel(const float* __restrict__ xt,
                                                    const float* __restrict__ om,
                                                    const float* __restrict__ wdT,
                                                    const float* __restrict__ b_def,
                                                    float* __restrict__ out) {
    __shared__ float s_wgt[9 * 64 * 4];   // [k][px][neighbor] bilinear wgt * mask * valid
    __shared__ int s_addr[9 * 64 * 4];    // [k][px][neighbor] clamped channels-last base
    __shared__ float s_cols[64 * CSTR];   // [c][px] cols chunk; reused as [oc][px] staging
    __shared__ float s_wch[64 * WSTR];    // [c][oc] weight chunk

    int t = threadIdx.x;
    int p0 = blockIdx.x * 64;
    int b = p0 / HWn;
    int rem = p0 - b * HWn;
    int h = rem / Wn;
    int w0 = rem - h * Wn;

    // ---- Phase 1: sampling metadata (576 items = 64px x 9 taps) ----
    for (int item = t; item < 576; item += 256) {
        int k = item >> 6;   // tap
        int px = item & 63;
        int w = w0 + px;
        int base = h * Wn + w;
        float offx = om[((size_t)b * 27 + k) * HWn + base];
        float offy = om[((size_t)b * 27 + 9 + k) * HWn + base];
        float mval = om[((size_t)b * 27 + 18 + k) * HWn + base];
        float ys = (float)(h + k / 3 - 1) + offy;
        float xs = (float)(w + k % 3 - 1) + offx;
        float y0f = floorf(ys), x0f = floorf(xs);
        float fy = ys - y0f, fx = xs - x0f;
        int y0 = (int)y0f, x0 = (int)x0f;
#pragma unroll
        for (int n = 0; n < 4; ++n) {
            int yy = y0 + (n >> 1);
            int xx = x0 + (n & 1);
            bool valid = (yy >= 0) && (yy < Hn) && (xx >= 0) && (xx < Wn);
            float wgt = ((n >> 1) ? fy : 1.f - fy) * ((n & 1) ? fx : 1.f - fx) * mval;
            int yc = min(max(yy, 0), Hn - 1);
            int xc = min(max(xx, 0), Wn - 1);
            s_wgt[(k * 64 + px) * 4 + n] = valid ? wgt : 0.f;
            s_addr[(k * 64 + px) * 4 + n] = (b * HWn + yc * Wn + xc) * Cn;
        }
    }
    __syncthreads();

    // ---- Phase 2: K-chunk loop over 9 taps (64 channels each) ----
    float accA[8], accB[8];  // (px, px+1) x 8 oc
#pragma unroll
    for (int j = 0; j < 8; ++j) { accA[j] = 0.f; accB[j] = 0.f; }

    int pxg = t & 31;
    int ocg = t >> 5;        // 0..7
    int mpx = pxg * 2;
    int oc0 = ocg * 8;

    int cw = t >> 2;            // w-chunk load: c row
    int woc0 = (t & 3) * 16;    // 16 oc per thread

    int spx = t & 63;           // cols compute: pixel
    int c0 = (t >> 6) * 16;     // 16 channels per thread

    for (int k = 0; k < 9; ++k) {
        // load w chunk [64c x 64oc] (coalesced float4)
        {
            const float4* src = (const float4*)(wdT + ((size_t)k * 64 + cw) * 64 + woc0);
            float4* dst = (float4*)&s_wch[cw * WSTR + woc0];
#pragma unroll
            for (int j = 0; j < 4; ++j) dst[j] = src[j];
        }
        // compute cols chunk [64c x 64px]
        {
            const float* wg = &s_wgt[(k * 64 + spx) * 4];
            const int* ad = &s_addr[(k * 64 + spx) * 4];
            float g0 = wg[0], g1 = wg[1], g2 = wg[2], g3 = wg[3];
            int a0 = ad[0], a1 = ad[1], a2 = ad[2], a3 = ad[3];
#pragma unroll
            for (int cc = 0; cc < 4; ++cc) {
                int c = c0 + cc * 4;
                float4 v0 = *(const float4*)(xt + a0 + c);
                float4 v1 = *(const float4*)(xt + a1 + c);
                float4 v2 = *(const float4*)(xt + a2 + c);
                float4 v3 = *(const float4*)(xt + a3 + c);
                float r0 = g0 * v0.x + g1 * v1.x + g2 * v2.x + g3 * v3.x;
                float r1 = g0 * v0.y + g1 * v1.y + g2 * v2.y + g3 * v3.y;
                float r2 = g0 * v0.z + g1 * v1.z + g2 * v2.z + g3 * v3.z;
                float r3 = g0 * v0.w + g1 * v1.w + g2 * v2.w + g3 * v3.w;
                s_cols[(c + 0) * CSTR + spx] = r0;
                s_cols[(c + 1) * CSTR + spx] = r1;
                s_cols[(c + 2) * CSTR + spx] = r2;
                s_cols[(c + 3) * CSTR + spx] = r3;
            }
        }
        __syncthreads();

        // MAC: 2px x 8oc per thread over 64 channels
#pragma unroll 4
        for (int c = 0; c < 64; ++c) {
            float2 cp = *(const float2*)&s_cols[c * CSTR + mpx];
            float4 wA = *(const float4*)&s_wch[c * WSTR + oc0];
            float4 wB = *(const float4*)&s_wch[c * WSTR + oc0 + 4];
            accA[0] += cp.x * wA.x; accA[1] += cp.x * wA.y;
            accA[2] += cp.x * wA.z; accA[3] += cp.x * wA.w;
            accA[4] += cp.x * wB.x; accA[5] += cp.x * wB.y;
            accA[6] += cp.x * wB.z; accA[7] += cp.x * wB.w;
            accB[0] += cp.y * wA.x; accB[1] += cp.y * wA.y;
            accB[2] += cp.y * wA.z; accB[3] += cp.y * wA.w;
            accB[4] += cp.y * wB.x; accB[5] += cp.y * wB.y;
            accB[6] += cp.y * wB.z; accB[7] += cp.y * wB.w;
        }
        __syncthreads();
    }

    // ---- Epilogue: bias + ReLU, LDS transpose, coalesced store ----
#pragma unroll
    for (int j = 0; j < 8; ++j) {
        int oc = oc0 + j;
        float bv = b_def[oc];
        float2 vv;
        vv.x = fmaxf(accA[j] + bv, 0.f);
        vv.y = fmaxf(accB[j] + bv, 0.f);
        *(float2*)&s_cols[oc * CSTR + mpx] = vv;  // staging as [oc][px]
    }
    __syncthreads();

    int px_l = t & 63;
    int og = t >> 6;  // 0..3
    float* ob = out + (((size_t)b * On) * Hn + h) * Wn + w0;
#pragma unroll
    for (int j = 0; j < 16; ++j) {
        int oc = og * 16 + j;
        ob[(size_t)oc * HWn + px_l] = s_cols[oc * CSTR + px_l];
    }
}

// ---------------------------------------------------------------------------
extern "C" void kernel_launch(void* const* d_in, const int* in_sizes, int n_in,
                              void* d_out, int out_size, void* d_ws, size_t ws_size,
                              hipStream_t stream) {
    const float* x = (const float*)d_in[0];
    const float* feat = (const float*)d_in[1];
    const float* w_off = (const float*)d_in[2];
    const float* b_off = (const float*)d_in[3];
    const float* w_def = (const float*)d_in[4];
    const float* b_def = (const float*)d_in[5];
    float* out = (float*)d_out;

    char* ws = (char*)d_ws;
    float* xt = (float*)ws;                                    // 16 MB: [B,HW,C]
    float* om = (float*)(ws + 16777216);                       // 6.75 MB: [B,27,H,W]
    float* wdT = (float*)(ws + 16777216 + 7077888);            // 144 KB: [9,64,64]

    hipLaunchKernelGGL(transpose_x_kernel, dim3(HWn / 64, Bn), dim3(256), 0, stream, x, xt);
    hipLaunchKernelGGL(transpose_w_kernel, dim3(144), dim3(256), 0, stream, w_def, wdT);
    hipLaunchKernelGGL(off_conv_kernel, dim3(Hn, Bn), dim3(128), 0, stream, feat, w_off, b_off, om);
    hipLaunchKernelGGL(fused_kernel, dim3((Bn * HWn) / 64), dim3(256), 0, stream,
                       xt, om, wdT, b_def, out);
}

// Round 2
// 159.283 us; speedup vs baseline: 1.9593x; 1.9593x over previous
//
#include <hip/hip_runtime.h>
#include <math.h>

#define Bn 4
#define Cn 64
#define On 64
#define Hn 128
#define Wn 128
#define HWn (Hn * Wn)
#define AST 72  // bf16 LDS row stride: 144 B -> 16B-aligned b128, 2-way-free banks

typedef __attribute__((ext_vector_type(8))) short s16x8;
typedef __attribute__((ext_vector_type(4))) float f32x4;

__device__ __forceinline__ unsigned short f2bf(float f) {
    unsigned u = __float_as_uint(f);
    u += 0x7fffu + ((u >> 16) & 1u);  // RTNE (finite values)
    return (unsigned short)(u >> 16);
}
__device__ __forceinline__ float bf2f(unsigned short u) {
    return __uint_as_float(((unsigned)u) << 16);
}

// ---------------------------------------------------------------------------
// Kernel 1: x [B,C,H,W] f32 -> xt [B,HW,C] bf16 (channels-last gathers)
// ---------------------------------------------------------------------------
__global__ __launch_bounds__(256) void transpose_x_kernel(const float* __restrict__ x,
                                                          ushort* __restrict__ xt) {
    __shared__ float tile[64][65];
    int b = blockIdx.y, hw0 = blockIdx.x * 64, t = threadIdx.x;
    int lane = t & 63, grp = t >> 6;
    const float* xb = x + (size_t)b * Cn * HWn;
#pragma unroll
    for (int i = 0; i < 16; ++i) {
        int c = grp * 16 + i;
        tile[lane][c] = xb[(size_t)c * HWn + hw0 + lane];  // coalesced along hw
    }
    __syncthreads();
    int hw = t & 63, c0 = (t >> 6) * 16;
    ushort* dst = xt + ((size_t)(b * HWn + hw0 + hw)) * Cn + c0;
    s16x8 p0, p1;
#pragma unroll
    for (int j = 0; j < 8; ++j) {
        p0[j] = (short)f2bf(tile[hw][c0 + j]);
        p1[j] = (short)f2bf(tile[hw][c0 + 8 + j]);
    }
    *(s16x8*)dst = p0;
    *(s16x8*)(dst + 8) = p1;
}

// ---------------------------------------------------------------------------
// Kernel 2: weights -> bf16, [k][oc][c] layouts.
// wdT: [9][64][64] from w_def [64,64,3,3]; woT: [9][32][64] from w_off (oc>=27 -> 0)
// ---------------------------------------------------------------------------
__global__ __launch_bounds__(256) void transpose_w_kernel(const float* __restrict__ wdef,
                                                          const float* __restrict__ woff,
                                                          ushort* __restrict__ wdT,
                                                          ushort* __restrict__ woT) {
    int idx = blockIdx.x * 256 + threadIdx.x;
    if (idx < 9 * 64 * 64) {
        int c = idx & 63, oc = (idx >> 6) & 63, k = idx >> 12;
        wdT[idx] = f2bf(wdef[(oc * 64 + c) * 9 + k]);
    } else if (idx < 9 * 64 * 64 + 9 * 32 * 64) {
        int i2 = idx - 9 * 64 * 64;
        int c = i2 & 63, oc = (i2 >> 6) & 31, k = i2 >> 11;
        woT[i2] = (oc < 27) ? f2bf(woff[(oc * 64 + c) * 9 + k]) : (ushort)0;
    }
}

// ---------------------------------------------------------------------------
// Kernel 3: offset conv as MFMA GEMM. Tile = 128 px (one row) x 32 oc (27 used).
// om layout: [B][27][H][W]; planes 0..8 off_x, 9..17 off_y, 18..26 mask(sigmoid).
// ---------------------------------------------------------------------------
__global__ __launch_bounds__(256) void off_conv_mfma(const float* __restrict__ feat,
                                                     const ushort* __restrict__ woT,
                                                     const float* __restrict__ b_off,
                                                     float* __restrict__ om) {
    __shared__ __align__(16) char smem[18432 + 4608];
    ushort* s_a = (ushort*)smem;             // [128][AST] bf16 cols
    ushort* s_b = (ushort*)(smem + 18432);   // [32][AST] bf16 weights
    float* s_out = (float*)smem;             // [32][132] f32, aliases s_a post-loop

    int t = threadIdx.x;
    int h = blockIdx.x, b = blockIdx.y;
    int lane = t & 63, wv = t >> 6;

    f32x4 zero = {0.f, 0.f, 0.f, 0.f};
    f32x4 acc[2][2];
    acc[0][0] = zero; acc[0][1] = zero; acc[1][0] = zero; acc[1][1] = zero;

    int apx = t & 127;          // A-build pixel (= x coordinate)
    int acg = (t >> 7) * 32;    // A-build channel base: 0 or 32

    for (int k = 0; k < 9; ++k) {
        int dy = k / 3 - 1, dx = k % 3 - 1;
        int y = h + dy, xx = apx + dx;
        bool valid = (y >= 0) && (y < Hn) && (xx >= 0) && (xx < Wn);
        const float* fp = feat + (((size_t)b * Cn + acg) * HWn + y * Wn + xx);
#pragma unroll
        for (int cc = 0; cc < 4; ++cc) {
            s16x8 p;
#pragma unroll
            for (int j = 0; j < 8; ++j) {
                float v = valid ? fp[(cc * 8 + j) * HWn] : 0.f;
                p[j] = (short)f2bf(v);
            }
            *(s16x8*)&s_a[apx * AST + acg + cc * 8] = p;
        }
        if (t < 128) {
            int oc = t >> 2, c0 = (t & 3) * 16;
            const ushort* src = woT + ((k * 32 + oc) * 64 + c0);
            *(s16x8*)&s_b[oc * AST + c0] = *(const s16x8*)src;
            *(s16x8*)&s_b[oc * AST + c0 + 8] = *(const s16x8*)(src + 8);
        }
        __syncthreads();
#pragma unroll
        for (int s = 0; s < 2; ++s) {
            int c0 = s * 32 + (lane >> 4) * 8;
#pragma unroll
            for (int pi = 0; pi < 2; ++pi) {
                s16x8 av = *(const s16x8*)&s_a[(wv * 32 + pi * 16 + (lane & 15)) * AST + c0];
#pragma unroll
                for (int oi = 0; oi < 2; ++oi) {
                    s16x8 bv = *(const s16x8*)&s_b[(oi * 16 + (lane & 15)) * AST + c0];
                    acc[pi][oi] = __builtin_amdgcn_mfma_f32_16x16x32_bf16(av, bv, acc[pi][oi], 0, 0, 0);
                }
            }
        }
        __syncthreads();
    }

    // epilogue: bias + sigmoid(mask planes), stage [oc][px], coalesced store
#pragma unroll
    for (int pi = 0; pi < 2; ++pi)
#pragma unroll
        for (int oi = 0; oi < 2; ++oi) {
            int oc = oi * 16 + (lane & 15);
#pragma unroll
            for (int r = 0; r < 4; ++r) {
                int px = wv * 32 + pi * 16 + (lane >> 4) * 4 + r;
                float v = acc[pi][oi][r];
                if (oc < 27) {
                    v += b_off[oc];
                    if (oc >= 18) v = 1.f / (1.f + __expf(-v));
                }
                s_out[oc * 132 + px] = v;
            }
        }
    __syncthreads();
#pragma unroll
    for (int j = 0; j < 16; ++j) {
        int idx = t + 256 * j;  // 0..4095
        int oc = idx >> 7, px = idx & 127;
        if (oc < 27) om[((size_t)b * 27 + oc) * HWn + h * Wn + px] = s_out[oc * 132 + px];
    }
}

// ---------------------------------------------------------------------------
// Kernel 4: fused deformable sampling + MFMA GEMM [64px x 64oc] x K=576.
// ---------------------------------------------------------------------------
__global__ __launch_bounds__(256) void fused_mfma(const ushort* __restrict__ xt,
                                                  const float* __restrict__ om,
                                                  const ushort* __restrict__ wdT,
                                                  const float* __restrict__ b_def,
                                                  float* __restrict__ out) {
    __shared__ __align__(16) char smem[36864];
    float* s_wgt = (float*)smem;             // [9][64][4]
    int* s_addr = (int*)(smem + 9216);       // [9][64][4]
    ushort* s_a = (ushort*)(smem + 18432);   // [64][AST] bf16 cols
    ushort* s_b = (ushort*)(smem + 27648);   // [64][AST] bf16 weights
    float* s_out = (float*)smem;             // [64][66] f32, aliases wgt/addr post-loop

    int t = threadIdx.x;
    int p0 = blockIdx.x * 64;
    int b = p0 / HWn;
    int rem = p0 - b * HWn;
    int h = rem / Wn, w0 = rem - h * Wn;
    int lane = t & 63, wv = t >> 6;

    // ---- Phase 1: sampling metadata (64px x 9 taps) ----
    for (int item = t; item < 576; item += 256) {
        int k = item >> 6, px = item & 63;
        int w = w0 + px;
        int base = h * Wn + w;
        float offx = om[((size_t)b * 27 + k) * HWn + base];
        float offy = om[((size_t)b * 27 + 9 + k) * HWn + base];
        float mval = om[((size_t)b * 27 + 18 + k) * HWn + base];
        float ys = (float)(h + k / 3 - 1) + offy;
        float xs = (float)(w + k % 3 - 1) + offx;
        float y0f = floorf(ys), x0f = floorf(xs);
        float fy = ys - y0f, fx = xs - x0f;
        int y0 = (int)y0f, x0 = (int)x0f;
#pragma unroll
        for (int n = 0; n < 4; ++n) {
            int yy = y0 + (n >> 1), xx2 = x0 + (n & 1);
            bool valid = (yy >= 0) && (yy < Hn) && (xx2 >= 0) && (xx2 < Wn);
            float wgt = ((n >> 1) ? fy : 1.f - fy) * ((n & 1) ? fx : 1.f - fx) * mval;
            int yc = min(max(yy, 0), Hn - 1), xc = min(max(xx2, 0), Wn - 1);
            s_wgt[(k * 64 + px) * 4 + n] = valid ? wgt : 0.f;
            s_addr[(k * 64 + px) * 4 + n] = (b * HWn + yc * Wn + xc) * Cn;
        }
    }
    __syncthreads();

    f32x4 zero = {0.f, 0.f, 0.f, 0.f};
    f32x4 acc[4];
    acc[0] = zero; acc[1] = zero; acc[2] = zero; acc[3] = zero;

    int spx = t & 63;          // A-build pixel
    int c0b = (t >> 6) * 16;   // A-build channel base

    for (int k = 0; k < 9; ++k) {
        // B stage: [64oc][64c] bf16 from wdT
        {
            int oc = t >> 2, c0 = (t & 3) * 16;
            const ushort* src = wdT + ((k * 64 + oc) * 64 + c0);
            *(s16x8*)&s_b[oc * AST + c0] = *(const s16x8*)src;
            *(s16x8*)&s_b[oc * AST + c0 + 8] = *(const s16x8*)(src + 8);
        }
        // A stage: bilinear gather -> bf16 cols [px][c]
        {
            const float* wg = &s_wgt[(k * 64 + spx) * 4];
            const int* ad = &s_addr[(k * 64 + spx) * 4];
            float g0 = wg[0], g1 = wg[1], g2 = wg[2], g3 = wg[3];
            int a0 = ad[0], a1 = ad[1], a2 = ad[2], a3 = ad[3];
#pragma unroll
            for (int cc = 0; cc < 2; ++cc) {
                int c = c0b + cc * 8;
                s16x8 q0 = *(const s16x8*)(xt + a0 + c);
                s16x8 q1 = *(const s16x8*)(xt + a1 + c);
                s16x8 q2 = *(const s16x8*)(xt + a2 + c);
                s16x8 q3 = *(const s16x8*)(xt + a3 + c);
                s16x8 p;
#pragma unroll
                for (int j = 0; j < 8; ++j) {
                    float r = g0 * bf2f((unsigned short)q0[j]) + g1 * bf2f((unsigned short)q1[j])
                            + g2 * bf2f((unsigned short)q2[j]) + g3 * bf2f((unsigned short)q3[j]);
                    p[j] = (short)f2bf(r);
                }
                *(s16x8*)&s_a[spx * AST + c] = p;
            }
        }
        __syncthreads();
        // MFMA: wave wv -> px block 16*wv, all 64 oc (4 tiles)
#pragma unroll
        for (int s = 0; s < 2; ++s) {
            int c0 = s * 32 + (lane >> 4) * 8;
            s16x8 av = *(const s16x8*)&s_a[(wv * 16 + (lane & 15)) * AST + c0];
#pragma unroll
            for (int ot = 0; ot < 4; ++ot) {
                s16x8 bv = *(const s16x8*)&s_b[(ot * 16 + (lane & 15)) * AST + c0];
                acc[ot] = __builtin_amdgcn_mfma_f32_16x16x32_bf16(av, bv, acc[ot], 0, 0, 0);
            }
        }
        __syncthreads();
    }

    // ---- Epilogue: bias + ReLU, stage [oc][px], coalesced store ----
#pragma unroll
    for (int ot = 0; ot < 4; ++ot) {
        int oc = ot * 16 + (lane & 15);
        float bv = b_def[oc];
#pragma unroll
        for (int r = 0; r < 4; ++r) {
            int px = wv * 16 + (lane >> 4) * 4 + r;
            s_out[oc * 66 + px] = fmaxf(acc[ot][r] + bv, 0.f);
        }
    }
    __syncthreads();
    {
        int px = t & 63, og = t >> 6;
        float* ob = out + ((size_t)b * On) * HWn + h * Wn + w0;
#pragma unroll
        for (int j = 0; j < 16; ++j) {
            int oc = og * 16 + j;
            ob[(size_t)oc * HWn + px] = s_out[oc * 66 + px];
        }
    }
}

// ---------------------------------------------------------------------------
extern "C" void kernel_launch(void* const* d_in, const int* in_sizes, int n_in,
                              void* d_out, int out_size, void* d_ws, size_t ws_size,
                              hipStream_t stream) {
    const float* x = (const float*)d_in[0];
    const float* feat = (const float*)d_in[1];
    const float* w_off = (const float*)d_in[2];
    const float* b_off = (const float*)d_in[3];
    const float* w_def = (const float*)d_in[4];
    const float* b_def = (const float*)d_in[5];
    float* out = (float*)d_out;

    char* ws = (char*)d_ws;
    ushort* xt = (ushort*)ws;                              // 8 MB: [B,HW,C] bf16
    float* om = (float*)(ws + 8388608);                    // 6.75 MB: [B,27,H,W] f32
    ushort* wdT = (ushort*)(ws + 8388608 + 7077888);       // 72 KB: [9,64,64] bf16
    ushort* woT = (ushort*)(ws + 8388608 + 7077888 + 73728);  // 36 KB: [9,32,64] bf16

    hipLaunchKernelGGL(transpose_x_kernel, dim3(HWn / 64, Bn), dim3(256), 0, stream, x, xt);
    hipLaunchKernelGGL(transpose_w_kernel, dim3(216), dim3(256), 0, stream, w_def, w_off, wdT, woT);
    hipLaunchKernelGGL(off_conv_mfma, dim3(Hn, Bn), dim3(256), 0, stream, feat, woT, b_off, om);
    hipLaunchKernelGGL(fused_mfma, dim3((Bn * HWn) / 64), dim3(256), 0, stream,
                       xt, om, wdT, b_def, out);
}